// Round 1
// baseline (861.505 us; speedup 1.0000x reference)
//
#include <hip/hip_runtime.h>

#define N_PTS 65536
#define CH    64
#define KNN   16
#define NBLK  2
#define BN_EPS 1e-5f

// ---------------------------------------------------------------------------
// histogram of reference_index (weights for the NK-row BatchNorm stats)
__global__ __launch_bounds__(256) void hist_kernel(const int* __restrict__ ref,
                                                   unsigned* __restrict__ cnt,
                                                   int total) {
    int i = blockIdx.x * 256 + threadIdx.x;
    if (i < total) atomicAdd(&cnt[ref[i]], 1u);
}

// ---------------------------------------------------------------------------
// out[r,:] = (pre-op(in[r,:])) @ W^T (+ bias)
// pre-op: if scale != null: x = relu(x*scale + shift)  (channelwise affine BN)
// W is [64][64] row-major as given (y_c = sum_k x_k * W[c][k]).
// 1 thread = 1 row; W transposed into LDS; broadcast float4 reads.
__global__ __launch_bounds__(256) void fused_bn_matmul(
    const float* __restrict__ in, const float* __restrict__ Wg,
    const float* __restrict__ bias, const float* __restrict__ scale,
    const float* __restrict__ shift, float* __restrict__ out)
{
    __shared__ float Wt[64][64];   // Wt[k][c] = Wg[c*64+k]
    const int tid = threadIdx.x;
    #pragma unroll
    for (int i = 0; i < 16; ++i) {
        int idx = tid + i * 256;
        Wt[idx & 63][idx >> 6] = Wg[idx];
    }
    __syncthreads();

    const size_t r = (size_t)blockIdx.x * 256 + tid;
    const float4* inr = (const float4*)(in + r * CH);

    float acc[64];
    #pragma unroll
    for (int c = 0; c < 64; ++c) acc[c] = bias ? bias[c] : 0.f;

    for (int kb = 0; kb < 64; kb += 8) {     // runtime loop, static inner indexing
        float4 a = inr[(kb >> 2) + 0];
        float4 b = inr[(kb >> 2) + 1];
        float xk[8] = {a.x, a.y, a.z, a.w, b.x, b.y, b.z, b.w};
        if (scale) {
            #pragma unroll
            for (int j = 0; j < 8; ++j)
                xk[j] = fmaxf(xk[j] * scale[kb + j] + shift[kb + j], 0.f);
        }
        #pragma unroll
        for (int j = 0; j < 8; ++j) {
            const float4* wr = (const float4*)(&Wt[kb + j][0]);
            #pragma unroll
            for (int c4 = 0; c4 < 16; ++c4) {
                float4 w = wr[c4];
                acc[c4 * 4 + 0] = fmaf(xk[j], w.x, acc[c4 * 4 + 0]);
                acc[c4 * 4 + 1] = fmaf(xk[j], w.y, acc[c4 * 4 + 1]);
                acc[c4 * 4 + 2] = fmaf(xk[j], w.z, acc[c4 * 4 + 2]);
                acc[c4 * 4 + 3] = fmaf(xk[j], w.w, acc[c4 * 4 + 3]);
            }
        }
    }

    float4* outr = (float4*)(out + r * CH);
    #pragma unroll
    for (int i = 0; i < 16; ++i)
        outr[i] = make_float4(acc[4*i], acc[4*i+1], acc[4*i+2], acc[4*i+3]);
}

// ---------------------------------------------------------------------------
// per-channel (weighted) sum / sumsq.  thread: channel = tid&63, wave = 1 row.
__global__ __launch_bounds__(256) void col_stats(
    const float* __restrict__ y, const unsigned* __restrict__ cnt,
    float* __restrict__ sum, float* __restrict__ ss, int nrows)
{
    const int tid = threadIdx.x;
    const int c  = tid & 63;
    const int wv = tid >> 6;
    float s = 0.f, q = 0.f;
    for (int r = blockIdx.x * 4 + wv; r < nrows; r += gridDim.x * 4) {
        float v = y[(size_t)r * CH + c];
        float w = cnt ? (float)cnt[r] : 1.f;
        s += w * v;
        q += w * v * v;
    }
    __shared__ float lsum[256], lss[256];
    lsum[tid] = s; lss[tid] = q;
    __syncthreads();
    if (tid < 64) {
        atomicAdd(&sum[tid], lsum[tid] + lsum[tid+64] + lsum[tid+128] + lsum[tid+192]);
        atomicAdd(&ss[tid],  lss[tid]  + lss[tid+64]  + lss[tid+128]  + lss[tid+192]);
    }
}

// ---------------------------------------------------------------------------
// fold BN params: scale = g*rsqrt(var+eps), shift = b - mean*scale; zero accums.
__global__ void bn_finalize(float* __restrict__ sum, float* __restrict__ ss,
                            const float* __restrict__ g, const float* __restrict__ b,
                            float inv_denom, float* __restrict__ scale,
                            float* __restrict__ shift)
{
    int c = threadIdx.x;   // 64 threads
    float m  = sum[c] * inv_denom;
    float v  = ss[c] * inv_denom - m * m;
    float rs = rsqrtf(v + BN_EPS);
    float sc = g[c] * rs;
    scale[c] = sc;
    shift[c] = b[c] - m * sc;
    sum[c] = 0.f; ss[c] = 0.f;
}

// ---------------------------------------------------------------------------
// xm[n,c] = max_k relu(bn(y3[ref[n,k],c])); inline unweighted stats of xm.
// wave per row: lane = channel -> coalesced 256B row reads (L2/LLC resident).
__global__ __launch_bounds__(256) void gather_max_bn(
    const float* __restrict__ y3, const int* __restrict__ ref,
    const float* __restrict__ scale, const float* __restrict__ shift,
    float* __restrict__ xm, float* __restrict__ sum, float* __restrict__ ss,
    int nrows)
{
    const int tid  = threadIdx.x;
    const int lane = tid & 63;
    const int wv   = tid >> 6;
    const float sc = scale[lane], sh = shift[lane];
    float s = 0.f, q = 0.f;
    for (int r = blockIdx.x * 4 + wv; r < nrows; r += gridDim.x * 4) {
        float mx = 0.f;   // relu outputs are >= 0, so 0 is the identity
        #pragma unroll
        for (int k = 0; k < KNN; ++k) {
            int j = ref[r * KNN + k];
            float v = y3[(size_t)j * CH + lane];
            mx = fmaxf(mx, fmaxf(v * sc + sh, 0.f));
        }
        xm[(size_t)r * CH + lane] = mx;
        s += mx; q += mx * mx;
    }
    __shared__ float lsum[256], lss[256];
    lsum[tid] = s; lss[tid] = q;
    __syncthreads();
    if (tid < 64) {
        atomicAdd(&sum[tid], lsum[tid] + lsum[tid+64] + lsum[tid+128] + lsum[tid+192]);
        atomicAdd(&ss[tid],  lss[tid]  + lss[tid+64]  + lss[tid+128]  + lss[tid+192]);
    }
}

// ---------------------------------------------------------------------------
// dst = relu(identity + y4*scale + shift)   (elementwise, float4)
__global__ __launch_bounds__(256) void residual_bn_relu(
    const float* __restrict__ identity, const float* __restrict__ y4,
    const float* __restrict__ scale, const float* __restrict__ shift,
    float* __restrict__ dst, int total4)
{
    int i = blockIdx.x * 256 + threadIdx.x;
    if (i >= total4) return;
    int c0 = (i * 4) & 63;
    float4 idv = ((const float4*)identity)[i];
    float4 yv  = ((const float4*)y4)[i];
    float4 o;
    o.x = fmaxf(idv.x + yv.x * scale[c0+0] + shift[c0+0], 0.f);
    o.y = fmaxf(idv.y + yv.y * scale[c0+1] + shift[c0+1], 0.f);
    o.z = fmaxf(idv.z + yv.z * scale[c0+2] + shift[c0+2], 0.f);
    o.w = fmaxf(idv.w + yv.w * scale[c0+3] + shift[c0+3], 0.f);
    ((float4*)dst)[i] = o;
}

// ---------------------------------------------------------------------------
extern "C" void kernel_launch(void* const* d_in, const int* in_sizes, int n_in,
                              void* d_out, int out_size, void* d_ws, size_t ws_size,
                              hipStream_t stream)
{
    const float* feat    = (const float*)d_in[1];
    const int*   ref     = (const int*)  d_in[2];
    const float* fc1_w   = (const float*)d_in[3];
    const float* bn1_g   = (const float*)d_in[4];
    const float* bn1_b   = (const float*)d_in[5];
    const float* la_w1   = (const float*)d_in[6];
    const float* la_b1   = (const float*)d_in[7];
    const float* la_bn1g = (const float*)d_in[8];
    const float* la_bn1b = (const float*)d_in[9];
    const float* la_w2   = (const float*)d_in[10];
    const float* la_b2   = (const float*)d_in[11];
    const float* la_bn2g = (const float*)d_in[12];
    const float* la_bn2b = (const float*)d_in[13];
    const float* fc3_w   = (const float*)d_in[14];
    const float* bn2_g   = (const float*)d_in[15];
    const float* bn2_b   = (const float*)d_in[16];
    const float* bn3_g   = (const float*)d_in[17];
    const float* bn3_b   = (const float*)d_in[18];
    float* out = (float*)d_out;

    // workspace layout
    float*    yA  = (float*)d_ws;                       // N*64
    float*    yB  = yA + (size_t)N_PTS * CH;            // N*64
    unsigned* cnt = (unsigned*)(yB + (size_t)N_PTS * CH); // N
    float*    sum = (float*)(cnt + N_PTS);              // 64
    float*    ss  = sum + 64;                           // 64
    float*    scl = ss + 64;                            // 64
    float*    shf = scl + 64;                           // 64

    hipMemsetAsync(cnt, 0, N_PTS * sizeof(unsigned), stream);
    hipMemsetAsync(sum, 0, 128 * sizeof(float), stream);
    hist_kernel<<<(N_PTS * KNN) / 256, 256, 0, stream>>>(ref, cnt, N_PTS * KNN);

    const float invN  = 1.f / (float)N_PTS;
    const float invNK = 1.f / (float)(N_PTS * KNN);

    const float* fsrc = feat;          // identity/input of current block
    for (int d = 0; d < NBLK; ++d) {
        const float* W1 = fc1_w + (size_t)d * CH * CH;
        const float* Wa = la_w1 + (size_t)d * CH * CH;
        const float* Wb = la_w2 + (size_t)d * CH * CH;
        const float* W3 = fc3_w + (size_t)d * CH * CH;

        // A: y1 = feat @ fc1^T  -> yA ; bn1 stats over N
        fused_bn_matmul<<<256, 256, 0, stream>>>(fsrc, W1, nullptr, nullptr, nullptr, yA);
        col_stats<<<2048, 256, 0, stream>>>(yA, nullptr, sum, ss, N_PTS);
        bn_finalize<<<1, 64, 0, stream>>>(sum, ss, bn1_g + d*CH, bn1_b + d*CH, invN, scl, shf);

        // B: y2 = relu(bn1(y1)) @ la_w1^T + la_b1 -> yB ; weighted stats (NK rows)
        fused_bn_matmul<<<256, 256, 0, stream>>>(yA, Wa, la_b1 + d*CH, scl, shf, yB);
        col_stats<<<2048, 256, 0, stream>>>(yB, cnt, sum, ss, N_PTS);
        bn_finalize<<<1, 64, 0, stream>>>(sum, ss, la_bn1g + d*CH, la_bn1b + d*CH, invNK, scl, shf);

        // C: y3 = relu(bnA(y2)) @ la_w2^T + la_b2 -> yA ; weighted stats
        fused_bn_matmul<<<256, 256, 0, stream>>>(yB, Wb, la_b2 + d*CH, scl, shf, yA);
        col_stats<<<2048, 256, 0, stream>>>(yA, cnt, sum, ss, N_PTS);
        bn_finalize<<<1, 64, 0, stream>>>(sum, ss, la_bn2g + d*CH, la_bn2b + d*CH, invNK, scl, shf);

        // E: xm = max_k relu(bnB(y3[ref])) -> yB ; inline stats over N
        gather_max_bn<<<2048, 256, 0, stream>>>(yA, ref, scl, shf, yB, sum, ss, N_PTS);
        bn_finalize<<<1, 64, 0, stream>>>(sum, ss, bn2_g + d*CH, bn2_b + d*CH, invN, scl, shf);

        // F: y4 = relu(bn2(xm)) @ fc3^T -> yA ; bn3 stats over N
        fused_bn_matmul<<<256, 256, 0, stream>>>(yB, W3, nullptr, scl, shf, yA);
        col_stats<<<2048, 256, 0, stream>>>(yA, nullptr, sum, ss, N_PTS);
        bn_finalize<<<1, 64, 0, stream>>>(sum, ss, bn3_g + d*CH, bn3_b + d*CH, invN, scl, shf);

        // G: feat' = relu(identity + bn3(y4)) -> out (in-place safe elementwise)
        residual_bn_relu<<<(N_PTS * CH / 4) / 256, 256, 0, stream>>>(
            fsrc, yA, scl, shf, out, N_PTS * CH / 4);

        fsrc = out;   // next block's identity/input
    }
}

// Round 3
// 487.005 us; speedup vs baseline: 1.7690x; 1.7690x over previous
//
#include <hip/hip_runtime.h>

#define N_PTS 65536
#define CH    64
#define KNN   16
#define BN_EPS 1e-5f

typedef __attribute__((ext_vector_type(8))) short bf16x8;
typedef __attribute__((ext_vector_type(4))) float f32x4;

__device__ __forceinline__ unsigned short f2bf(float f) {
    unsigned u = __builtin_bit_cast(unsigned, f);
    u += 0x7fffu + ((u >> 16) & 1u);          // round-to-nearest-even
    return (unsigned short)(u >> 16);
}
__device__ __forceinline__ float bf2f(unsigned short h) {
    unsigned u = ((unsigned)h) << 16;
    return __builtin_bit_cast(float, u);
}

// ---------------------------------------------------------------------------
__global__ __launch_bounds__(256) void hist_kernel(const int* __restrict__ ref,
                                                   unsigned* __restrict__ cnt,
                                                   int total) {
    int i = blockIdx.x * 256 + threadIdx.x;
    if (i < total) atomicAdd(&cnt[ref[i]], 1u);
}

// ---------------------------------------------------------------------------
// split all 8 weight matrices (fc1,la1,la2,fc3 x D=2) into bf16 hi/lo tables.
// layout: slot = kind*2 + d, each slot 4096 elems, same [c][k] order as input.
__global__ __launch_bounds__(256) void wconv_kernel(
    const float* __restrict__ fc1, const float* __restrict__ la1,
    const float* __restrict__ la2, const float* __restrict__ fc3,
    unsigned short* __restrict__ hi, unsigned short* __restrict__ lo)
{
    int i = blockIdx.x * 256 + threadIdx.x;   // 0..32767
    const float* p = (i < 8192) ? fc1 : (i < 16384) ? la1
                   : (i < 24576) ? la2 : fc3;
    float w = p[i & 8191];
    unsigned short h = f2bf(w);
    hi[i] = h;
    lo[i] = f2bf(w - bf2f(h));
}

// ---------------------------------------------------------------------------
// Fused (pre-op) -> 64x64 matmul (bf16x3 MFMA, ~fp32 accuracy) -> stats.
// PRE: 0 none; 1 x=relu(x*sc+sh); 2 x=relu(identity + x*sc+sh), write x->f1_out
// wave = 16-row m-tile; block = 4 waves = 64 rows; grid = 1024.
template<int PRE, int BIAS, int WTD>
__global__ __launch_bounds__(256) void mm_kernel(
    const float* __restrict__ in,    const float* __restrict__ identity,
    const unsigned short* __restrict__ whi, const unsigned short* __restrict__ wlo,
    const float* __restrict__ bias,
    const float* __restrict__ gg,    const float* __restrict__ bb,
    const float* __restrict__ S_in,  float inv_denom,
    float*       __restrict__ out,   float* __restrict__ S_out,
    const unsigned* __restrict__ cnt, float* __restrict__ f1_out)
{
    __shared__ float sc[64], sh[64];
    __shared__ float lsum[4][64], lss[4][64];
    const int tid = threadIdx.x;
    if (PRE >= 1) {
        if (tid < 64) {
            float m   = S_in[tid] * inv_denom;
            float var = S_in[64 + tid] * inv_denom - m * m;
            float s   = gg[tid] * rsqrtf(var + BN_EPS);
            sc[tid] = s; sh[tid] = bb[tid] - m * s;
        }
        __syncthreads();
    }
    const int lane = tid & 63, wid = tid >> 6;
    const int l15 = lane & 15, kg = lane >> 4;
    const int row0 = (blockIdx.x * 4 + wid) * 16;

    // ---- A row fragments: row = row0+l15, k = ks*32 + kg*8 + j ----
    const int arow = row0 + l15;
    const float* ap = in + (size_t)arow * 64 + kg * 8;
    float xv[2][8];
    #pragma unroll
    for (int ks = 0; ks < 2; ++ks) {
        float4 a0 = *(const float4*)(ap + ks * 32);
        float4 a1 = *(const float4*)(ap + ks * 32 + 4);
        xv[ks][0]=a0.x; xv[ks][1]=a0.y; xv[ks][2]=a0.z; xv[ks][3]=a0.w;
        xv[ks][4]=a1.x; xv[ks][5]=a1.y; xv[ks][6]=a1.z; xv[ks][7]=a1.w;
    }
    if (PRE == 1) {
        #pragma unroll
        for (int ks = 0; ks < 2; ++ks)
            #pragma unroll
            for (int j = 0; j < 8; ++j) {
                int k = ks * 32 + kg * 8 + j;
                xv[ks][j] = fmaxf(xv[ks][j] * sc[k] + sh[k], 0.f);
            }
    } else if (PRE == 2) {
        const float* idp = identity + (size_t)arow * 64 + kg * 8;
        float* f1p = f1_out + (size_t)arow * 64 + kg * 8;
        #pragma unroll
        for (int ks = 0; ks < 2; ++ks) {
            float4 i0 = *(const float4*)(idp + ks * 32);
            float4 i1 = *(const float4*)(idp + ks * 32 + 4);
            float idv[8] = {i0.x,i0.y,i0.z,i0.w,i1.x,i1.y,i1.z,i1.w};
            #pragma unroll
            for (int j = 0; j < 8; ++j) {
                int k = ks * 32 + kg * 8 + j;
                xv[ks][j] = fmaxf(idv[j] + xv[ks][j] * sc[k] + sh[k], 0.f);
            }
            *(float4*)(f1p + ks * 32)     = make_float4(xv[ks][0],xv[ks][1],xv[ks][2],xv[ks][3]);
            *(float4*)(f1p + ks * 32 + 4) = make_float4(xv[ks][4],xv[ks][5],xv[ks][6],xv[ks][7]);
        }
    }
    // split A into hi + lo bf16
    bf16x8 ahi[2], alo[2];
    #pragma unroll
    for (int ks = 0; ks < 2; ++ks) {
        bf16x8 th, tl;
        #pragma unroll
        for (int j = 0; j < 8; ++j) {
            unsigned short h = f2bf(xv[ks][j]);
            th[j] = (short)h;
            tl[j] = (short)f2bf(xv[ks][j] - bf2f(h));
        }
        ahi[ks] = th; alo[ks] = tl;
    }

    // ---- MFMA: D += Ahi@Whi + Alo@Whi + Ahi@Wlo ----
    f32x4 d[4];
    #pragma unroll
    for (int ct = 0; ct < 4; ++ct) {
        float bc = BIAS ? bias[ct * 16 + l15] : 0.f;
        d[ct] = (f32x4){bc, bc, bc, bc};
    }
    #pragma unroll
    for (int ct = 0; ct < 4; ++ct) {
        const unsigned short* hrow = whi + (ct * 16 + l15) * 64 + kg * 8;
        const unsigned short* lrow = wlo + (ct * 16 + l15) * 64 + kg * 8;
        #pragma unroll
        for (int ks = 0; ks < 2; ++ks) {
            bf16x8 wh = *(const bf16x8*)(hrow + ks * 32);
            bf16x8 wl = *(const bf16x8*)(lrow + ks * 32);
            d[ct] = __builtin_amdgcn_mfma_f32_16x16x32_bf16(ahi[ks], wh, d[ct], 0, 0, 0);
            d[ct] = __builtin_amdgcn_mfma_f32_16x16x32_bf16(alo[ks], wh, d[ct], 0, 0, 0);
            d[ct] = __builtin_amdgcn_mfma_f32_16x16x32_bf16(ahi[ks], wl, d[ct], 0, 0, 0);
        }
    }

    // ---- stats: D row = kg*4 + i, col = ct*16 + l15 ----
    float w[4] = {1.f, 1.f, 1.f, 1.f};
    if (WTD) {
        #pragma unroll
        for (int i = 0; i < 4; ++i) w[i] = (float)cnt[row0 + kg * 4 + i];
    }
    #pragma unroll
    for (int ct = 0; ct < 4; ++ct) {
        float t = 0.f, t2 = 0.f;
        #pragma unroll
        for (int i = 0; i < 4; ++i) {
            float v = d[ct][i];
            t += w[i] * v; t2 += w[i] * v * v;
        }
        t  += __shfl_xor(t, 16);  t  += __shfl_xor(t, 32);
        t2 += __shfl_xor(t2, 16); t2 += __shfl_xor(t2, 32);
        if (kg == 0) { lsum[wid][ct * 16 + l15] = t; lss[wid][ct * 16 + l15] = t2; }
    }
    __syncthreads();
    if (tid < 128) {
        int c = tid & 63;
        if (tid < 64) atomicAdd(&S_out[c],      lsum[0][c]+lsum[1][c]+lsum[2][c]+lsum[3][c]);
        else          atomicAdd(&S_out[64 + c], lss[0][c]+lss[1][c]+lss[2][c]+lss[3][c]);
    }

    // ---- store fp32 ----
    #pragma unroll
    for (int ct = 0; ct < 4; ++ct)
        #pragma unroll
        for (int i = 0; i < 4; ++i)
            out[(size_t)(row0 + kg * 4 + i) * 64 + ct * 16 + l15] = d[ct][i];
}

// ---------------------------------------------------------------------------
// xm[r,c] = relu(bn(max_k y3[ref[r,k],c]))  (bn monotone: gamma==1 > 0)
// wave = 1 row (lane = channel); 2 rows pipelined; inline stats over N.
__global__ __launch_bounds__(256) void gather_kernel(
    const float* __restrict__ y3, const int* __restrict__ ref,
    const float* __restrict__ S_in, float inv_denom,
    const float* __restrict__ gg, const float* __restrict__ bb,
    float* __restrict__ xm, float* __restrict__ S_out)
{
    __shared__ float sc_s[64], sh_s[64], Rs[256], Rq[256];
    const int tid = threadIdx.x;
    if (tid < 64) {
        float m   = S_in[tid] * inv_denom;
        float var = S_in[64 + tid] * inv_denom - m * m;
        float s   = gg[tid] * rsqrtf(var + BN_EPS);
        sc_s[tid] = s; sh_s[tid] = bb[tid] - m * s;
    }
    __syncthreads();
    const int lane = tid & 63, wid = tid >> 6;
    const float sc = sc_s[lane], sh = sh_s[lane];
    float s = 0.f, q = 0.f;
    const int base = blockIdx.x * 4 + wid;           // 0..8191
    #pragma unroll
    for (int it = 0; it < 4; ++it) {
        const int r0 = base + it * 16384;
        const int r1 = r0 + 8192;
        int jv0 = ref[r0 * 16 + (lane & 15)];
        int jv1 = ref[r1 * 16 + (lane & 15)];
        float v0[16], v1[16];
        #pragma unroll
        for (int t = 0; t < 16; ++t)
            v0[t] = y3[(size_t)__shfl(jv0, t) * 64 + lane];
        #pragma unroll
        for (int t = 0; t < 16; ++t)
            v1[t] = y3[(size_t)__shfl(jv1, t) * 64 + lane];
        float m0 = v0[0], m1 = v1[0];
        #pragma unroll
        for (int t = 1; t < 16; ++t) { m0 = fmaxf(m0, v0[t]); m1 = fmaxf(m1, v1[t]); }
        float x0 = fmaxf(m0 * sc + sh, 0.f);
        float x1 = fmaxf(m1 * sc + sh, 0.f);
        xm[(size_t)r0 * 64 + lane] = x0;
        xm[(size_t)r1 * 64 + lane] = x1;
        s += x0 + x1; q += x0 * x0 + x1 * x1;
    }
    Rs[tid] = s; Rq[tid] = q;
    __syncthreads();
    if (tid < 64) {
        atomicAdd(&S_out[tid],      Rs[tid]+Rs[tid+64]+Rs[tid+128]+Rs[tid+192]);
        atomicAdd(&S_out[64 + tid], Rq[tid]+Rq[tid+64]+Rq[tid+128]+Rq[tid+192]);
    }
}

// ---------------------------------------------------------------------------
// io = relu(io + y4*sc + sh)   (final residual, in place)
__global__ __launch_bounds__(256) void res_final(
    float* __restrict__ io, const float* __restrict__ y4,
    const float* __restrict__ S_in, float inv_denom,
    const float* __restrict__ gg, const float* __restrict__ bb)
{
    __shared__ float sc[64], sh[64];
    const int tid = threadIdx.x;
    if (tid < 64) {
        float m   = S_in[tid] * inv_denom;
        float var = S_in[64 + tid] * inv_denom - m * m;
        float s   = gg[tid] * rsqrtf(var + BN_EPS);
        sc[tid] = s; sh[tid] = bb[tid] - m * s;
    }
    __syncthreads();
    int i = blockIdx.x * 256 + tid;            // float4 index
    int c0 = (i * 4) & 63;
    float4 idv = ((const float4*)io)[i];
    float4 yv  = ((const float4*)y4)[i];
    float4 o;
    o.x = fmaxf(idv.x + yv.x * sc[c0+0] + sh[c0+0], 0.f);
    o.y = fmaxf(idv.y + yv.y * sc[c0+1] + sh[c0+1], 0.f);
    o.z = fmaxf(idv.z + yv.z * sc[c0+2] + sh[c0+2], 0.f);
    o.w = fmaxf(idv.w + yv.w * sc[c0+3] + sh[c0+3], 0.f);
    ((float4*)io)[i] = o;
}

// ---------------------------------------------------------------------------
extern "C" void kernel_launch(void* const* d_in, const int* in_sizes, int n_in,
                              void* d_out, int out_size, void* d_ws, size_t ws_size,
                              hipStream_t stream)
{
    const float* feat    = (const float*)d_in[1];
    const int*   ref     = (const int*)  d_in[2];
    const float* fc1_w   = (const float*)d_in[3];
    const float* bn1_g   = (const float*)d_in[4];
    const float* bn1_b   = (const float*)d_in[5];
    const float* la_w1   = (const float*)d_in[6];
    const float* la_b1   = (const float*)d_in[7];
    const float* la_bn1g = (const float*)d_in[8];
    const float* la_bn1b = (const float*)d_in[9];
    const float* la_w2   = (const float*)d_in[10];
    const float* la_b2   = (const float*)d_in[11];
    const float* la_bn2g = (const float*)d_in[12];
    const float* la_bn2b = (const float*)d_in[13];
    const float* fc3_w   = (const float*)d_in[14];
    const float* bn2_g   = (const float*)d_in[15];
    const float* bn2_b   = (const float*)d_in[16];
    const float* bn3_g   = (const float*)d_in[17];
    const float* bn3_b   = (const float*)d_in[18];
    float* out = (float*)d_out;

    // workspace: R1 16MB | R2 16MB | cnt 256KB | Sb 5KB | Whi 64KB | Wlo 64KB
    char* base = (char*)d_ws;
    float*    R1  = (float*)base;
    float*    R2  = (float*)(base + 16u * 1024 * 1024);
    unsigned* cnt = (unsigned*)(base + 32u * 1024 * 1024);
    float*    Sb  = (float*)(cnt + N_PTS);
    unsigned short* Whi = (unsigned short*)(Sb + 10 * 128);
    unsigned short* Wlo = Whi + 8 * 4096;
#define SS(i) (Sb + (i) * 128)
#define WH(kind, d) (Whi + ((kind) * 2 + (d)) * 4096)
#define WL(kind, d) (Wlo + ((kind) * 2 + (d)) * 4096)

    hipMemsetAsync(cnt, 0, N_PTS * sizeof(unsigned) + 10 * 128 * sizeof(float), stream);
    wconv_kernel<<<128, 256, 0, stream>>>(fc1_w, la_w1, la_w2, fc3_w, Whi, Wlo);
    hist_kernel<<<(N_PTS * KNN) / 256, 256, 0, stream>>>(ref, cnt, N_PTS * KNN);

    const float invN  = 1.f / (float)N_PTS;
    const float invNK = 1.f / (float)(N_PTS * KNN);
    const int MMG = N_PTS / 64;   // 1024 blocks

    // ---- block 0 ----
    mm_kernel<0,0,0><<<MMG,256,0,stream>>>(feat, nullptr, WH(0,0), WL(0,0), nullptr,
        nullptr, nullptr, nullptr, 0.f, R1, SS(0), nullptr, nullptr);
    mm_kernel<1,1,1><<<MMG,256,0,stream>>>(R1, nullptr, WH(1,0), WL(1,0), la_b1,
        bn1_g, bn1_b, SS(0), invN, R2, SS(1), cnt, nullptr);
    mm_kernel<1,1,1><<<MMG,256,0,stream>>>(R2, nullptr, WH(2,0), WL(2,0), la_b2,
        la_bn1g, la_bn1b, SS(1), invNK, R1, SS(2), cnt, nullptr);
    gather_kernel<<<2048,256,0,stream>>>(R1, ref, SS(2), invNK,
        la_bn2g, la_bn2b, R2, SS(3));
    mm_kernel<1,0,0><<<MMG,256,0,stream>>>(R2, nullptr, WH(3,0), WL(3,0), nullptr,
        bn2_g, bn2_b, SS(3), invN, R1, SS(4), nullptr, nullptr);

    // ---- block 1 (entry fuses block-0 residual; writes block-0 out) ----
    mm_kernel<2,0,0><<<MMG,256,0,stream>>>(R1, feat, WH(0,1), WL(0,1), nullptr,
        bn3_g, bn3_b, SS(4), invN, R2, SS(5), nullptr, out);
    mm_kernel<1,1,1><<<MMG,256,0,stream>>>(R2, nullptr, WH(1,1), WL(1,1), la_b1 + 64,
        bn1_g + 64, bn1_b + 64, SS(5), invN, R1, SS(6), cnt, nullptr);
    mm_kernel<1,1,1><<<MMG,256,0,stream>>>(R1, nullptr, WH(2,1), WL(2,1), la_b2 + 64,
        la_bn1g + 64, la_bn1b + 64, SS(6), invNK, R2, SS(7), cnt, nullptr);
    gather_kernel<<<2048,256,0,stream>>>(R2, ref, SS(7), invNK,
        la_bn2g + 64, la_bn2b + 64, R1, SS(8));
    mm_kernel<1,0,0><<<MMG,256,0,stream>>>(R1, nullptr, WH(3,1), WL(3,1), nullptr,
        bn2_g + 64, bn2_b + 64, SS(8), invN, R2, SS(9), nullptr, nullptr);
    res_final<<<(N_PTS * CH / 4) / 256, 256, 0, stream>>>(out, R2, SS(9), invN,
        bn3_g + 64, bn3_b + 64);
}